// Round 1
// baseline (119.527 us; speedup 1.0000x reference)
//
#include <hip/hip_runtime.h>
#include <hip/hip_bf16.h>

// Problem: B=8, T=4096, F=512
//   score = sigmoid(feat @ W + b)            [B,T]
//   peaks = local max along T (edge-replicated, >=)
//   hlens[b] = #peaks; feat_new = peak rows compacted to front, zero tail
// Outputs concatenated in d_out: feat_new (16777216 f32) then hlens (8, written as f32)

#define T_DIM 4096
#define F_DIM 512
#define B_DIM 8

// ---------------- Kernel 1: per-row dot + sigmoid ----------------
// one wave (64 lanes) per row; lane handles 8 consecutive floats (2x float4)
__global__ void __launch_bounds__(256) score_kernel(
    const float* __restrict__ feat, const float* __restrict__ W,
    const float* __restrict__ bias, float* __restrict__ score, int nrows) {
  int gtid = blockIdx.x * blockDim.x + threadIdx.x;
  int row  = gtid >> 6;
  int lane = threadIdx.x & 63;
  if (row >= nrows) return;

  const float4* fr = (const float4*)(feat + (size_t)row * F_DIM);
  const float4* wv = (const float4*)W;
  int i0 = lane * 2;
  float4 a0 = fr[i0];
  float4 a1 = fr[i0 + 1];
  float4 w0 = wv[i0];
  float4 w1 = wv[i0 + 1];
  float sum = a0.x * w0.x + a0.y * w0.y + a0.z * w0.z + a0.w * w0.w
            + a1.x * w1.x + a1.y * w1.y + a1.z * w1.z + a1.w * w1.w;

  // wave-64 butterfly reduce
  #pragma unroll
  for (int d = 32; d > 0; d >>= 1) sum += __shfl_xor(sum, d, 64);

  if (lane == 0) {
    float x = sum + bias[0];
    score[row] = 1.0f / (1.0f + expf(-x));
  }
}

// ---------------- Kernel 2: peaks + stable scan -> compaction indices ----------------
// one block per batch; 1024 threads; 4 elements per thread
__global__ void __launch_bounds__(1024) peaks_scan_kernel(
    const float* __restrict__ score, int* __restrict__ idx,
    int* __restrict__ hlens_i, float* __restrict__ hlens_f) {
  int b = blockIdx.x;
  __shared__ float s[T_DIM];
  __shared__ int wsum[16];

  const float* sb = score + b * T_DIM;
  int tid = threadIdx.x;  // 0..1023

  // vectorized load into LDS
  ((float4*)s)[tid] = ((const float4*)sb)[tid];
  __syncthreads();

  int t0 = tid * 4;
  int flags[4];
  int cnt = 0;
  #pragma unroll
  for (int j = 0; j < 4; j++) {
    int t = t0 + j;
    float c = s[t];
    float l = (t == 0) ? c : s[t - 1];
    float r = (t == T_DIM - 1) ? c : s[t + 1];
    flags[j] = (c >= l && c >= r) ? 1 : 0;
    cnt += flags[j];
  }

  // wave-64 inclusive scan of per-thread counts
  int lane = tid & 63;
  int wave = tid >> 6;
  int inc = cnt;
  #pragma unroll
  for (int d = 1; d < 64; d <<= 1) {
    int v = __shfl_up(inc, d, 64);
    if (lane >= d) inc += v;
  }
  if (lane == 63) wsum[wave] = inc;
  __syncthreads();

  if (tid == 0) {
    int acc = 0;
    #pragma unroll
    for (int w = 0; w < 16; w++) { int v = wsum[w]; wsum[w] = acc; acc += v; }
    hlens_i[b] = acc;
    hlens_f[b] = (float)acc;  // output buffer read as f32
  }
  __syncthreads();

  int base = wsum[wave] + inc - cnt;  // exclusive prefix for this thread
  int* ib = idx + b * T_DIM;
  #pragma unroll
  for (int j = 0; j < 4; j++) {
    if (flags[j]) ib[base++] = t0 + j;
  }
}

// ---------------- Kernel 3: gather compacted rows + zero tail ----------------
// one wave per output row
__global__ void __launch_bounds__(256) gather_kernel(
    const float* __restrict__ feat, const int* __restrict__ idx,
    const int* __restrict__ hlens_i, float* __restrict__ out, int nrows) {
  int gtid = blockIdx.x * blockDim.x + threadIdx.x;
  int row  = gtid >> 6;
  int lane = threadIdx.x & 63;
  if (row >= nrows) return;

  int b = row >> 12;       // /T_DIM
  int d = row & (T_DIM - 1);
  float4* orow = (float4*)(out + (size_t)row * F_DIM);
  int i0 = lane * 2;

  if (d < hlens_i[b]) {
    int src = idx[row];
    const float4* fr = (const float4*)(feat + ((size_t)(b << 12) + src) * F_DIM);
    orow[i0]     = fr[i0];
    orow[i0 + 1] = fr[i0 + 1];
  } else {
    float4 z = make_float4(0.f, 0.f, 0.f, 0.f);
    orow[i0]     = z;
    orow[i0 + 1] = z;
  }
}

extern "C" void kernel_launch(void* const* d_in, const int* in_sizes, int n_in,
                              void* d_out, int out_size, void* d_ws, size_t ws_size,
                              hipStream_t stream) {
  const float* feat = (const float*)d_in[0];
  const float* W    = (const float*)d_in[1];
  const float* bias = (const float*)d_in[2];

  float* out       = (float*)d_out;
  float* hlens_f   = out + (size_t)B_DIM * T_DIM * F_DIM;  // tail of d_out

  // workspace layout
  float* score   = (float*)d_ws;                          // 32768 f32
  int*   idx     = (int*)((char*)d_ws + 32768 * 4);       // 32768 i32
  int*   hlens_i = (int*)((char*)d_ws + 32768 * 8);       // 8 i32

  const int nrows = B_DIM * T_DIM;  // 32768

  // K1: scores. 4 waves/block -> 8192 blocks
  score_kernel<<<nrows / 4, 256, 0, stream>>>(feat, W, bias, score, nrows);

  // K2: peaks + scan per batch
  peaks_scan_kernel<<<B_DIM, 1024, 0, stream>>>(score, idx, hlens_i, hlens_f);

  // K3: gather + zero-fill
  gather_kernel<<<nrows / 4, 256, 0, stream>>>(feat, idx, hlens_i, out, nrows);
}

// Round 3
// 115.449 us; speedup vs baseline: 1.0353x; 1.0353x over previous
//
#include <hip/hip_runtime.h>
#include <hip/hip_bf16.h>

// Problem: B=8, T=4096, F=512
//   score = sigmoid(feat @ W + b)            [B,T]
//   peaks = local max along T (edge-replicated, >=)
//   hlens[b] = #peaks; feat_new = peak rows compacted to front, zero tail
// Outputs concatenated in d_out: feat_new (16777216 f32) then hlens (8, as f32)
//
// Structure (R2, resubmitted R3 after infra timeout): 2 kernels.
//   K1: score (unchanged from R1 — bit-exact, absmax was 0.0)
//   K2': fused peaks + per-batch stable scan (redundant per block) + gather.
//        256 blocks x 1024 thr; 32 slices/batch, 128 output rows/block.

#define T_DIM 4096
#define F_DIM 512
#define B_DIM 8

// ---------------- Kernel 1: per-row dot + sigmoid ----------------
// one wave (64 lanes) per row; lane handles 8 consecutive floats (2x float4)
__global__ void __launch_bounds__(256) score_kernel(
    const float* __restrict__ feat, const float* __restrict__ W,
    const float* __restrict__ bias, float* __restrict__ score, int nrows) {
  int gtid = blockIdx.x * blockDim.x + threadIdx.x;
  int row  = gtid >> 6;
  int lane = threadIdx.x & 63;
  if (row >= nrows) return;

  const float4* fr = (const float4*)(feat + (size_t)row * F_DIM);
  const float4* wv = (const float4*)W;
  int i0 = lane * 2;
  float4 a0 = fr[i0];
  float4 a1 = fr[i0 + 1];
  float4 w0 = wv[i0];
  float4 w1 = wv[i0 + 1];
  float sum = a0.x * w0.x + a0.y * w0.y + a0.z * w0.z + a0.w * w0.w
            + a1.x * w1.x + a1.y * w1.y + a1.z * w1.z + a1.w * w1.w;

  // wave-64 butterfly reduce
  #pragma unroll
  for (int d = 32; d > 0; d >>= 1) sum += __shfl_xor(sum, d, 64);

  if (lane == 0) {
    float x = sum + bias[0];
    score[row] = 1.0f / (1.0f + expf(-x));
  }
}

// ---------------- Kernel 2': peaks + scan (redundant per block) + gather ----
// grid = B_DIM * 32 blocks; block = 1024 threads (16 waves).
// block handles batch b = blockIdx.x>>5, output rows [slice*128, slice*128+128).
__global__ void __launch_bounds__(1024) scan_gather_kernel(
    const float* __restrict__ feat, const float* __restrict__ score,
    float* __restrict__ out, float* __restrict__ hlens_f) {
  int b     = blockIdx.x >> 5;
  int slice = blockIdx.x & 31;

  __shared__ float s[T_DIM];          // scores; later aliased as int idx[]
  __shared__ int   wsum[16];
  __shared__ int   total_s;
  int* sidx = (int*)s;                // alias (safe: sync between uses)

  int tid  = threadIdx.x;             // 0..1023
  int lane = tid & 63;
  int wave = tid >> 6;

  // load this batch's scores into LDS (16 KB, L2-resident after K1)
  ((float4*)s)[tid] = ((const float4*)(score + b * T_DIM))[tid];
  __syncthreads();

  // peak flags, 4 elements/thread
  int t0 = tid * 4;
  int flags[4];
  int cnt = 0;
  #pragma unroll
  for (int j = 0; j < 4; j++) {
    int t = t0 + j;
    float c = s[t];
    float l = (t == 0) ? c : s[t - 1];
    float r = (t == T_DIM - 1) ? c : s[t + 1];
    flags[j] = (c >= l && c >= r) ? 1 : 0;
    cnt += flags[j];
  }

  // wave-64 inclusive scan of per-thread counts
  int inc = cnt;
  #pragma unroll
  for (int d = 1; d < 64; d <<= 1) {
    int v = __shfl_up(inc, d, 64);
    if (lane >= d) inc += v;
  }
  if (lane == 63) wsum[wave] = inc;
  __syncthreads();   // all reads of s[] done; wsum[] complete

  if (tid == 0) {
    int acc = 0;
    #pragma unroll
    for (int w = 0; w < 16; w++) { int v = wsum[w]; wsum[w] = acc; acc += v; }
    total_s = acc;
    if (slice == 0) hlens_f[b] = (float)acc;   // hlens output (read as f32)
  }
  __syncthreads();

  // stable compaction: write source indices into LDS (aliases s[])
  int base = wsum[wave] + inc - cnt;  // exclusive prefix for this thread
  #pragma unroll
  for (int j = 0; j < 4; j++) {
    if (flags[j]) sidx[base++] = t0 + j;
  }
  __syncthreads();

  int total = total_s;

  // gather: 16 waves x 8 rows = 128 output rows for this slice
  const float* fb = feat + (size_t)b * T_DIM * F_DIM;
  float*       ob = out  + (size_t)b * T_DIM * F_DIM;
  #pragma unroll
  for (int r = 0; r < 8; r++) {
    int d = slice * 128 + wave * 8 + r;
    float4* orow = (float4*)(ob + (size_t)d * F_DIM);
    if (d < total) {
      const float4* fr = (const float4*)(fb + (size_t)sidx[d] * F_DIM);
      float4 v0 = fr[lane];
      float4 v1 = fr[lane + 64];
      orow[lane]      = v0;
      orow[lane + 64] = v1;
    } else {
      float4 z = make_float4(0.f, 0.f, 0.f, 0.f);
      orow[lane]      = z;
      orow[lane + 64] = z;
    }
  }
}

extern "C" void kernel_launch(void* const* d_in, const int* in_sizes, int n_in,
                              void* d_out, int out_size, void* d_ws, size_t ws_size,
                              hipStream_t stream) {
  const float* feat = (const float*)d_in[0];
  const float* W    = (const float*)d_in[1];
  const float* bias = (const float*)d_in[2];

  float* out     = (float*)d_out;
  float* hlens_f = out + (size_t)B_DIM * T_DIM * F_DIM;  // tail of d_out

  float* score = (float*)d_ws;  // 32768 f32 scratch

  const int nrows = B_DIM * T_DIM;  // 32768

  // K1: scores. 4 waves/block -> 8192 blocks
  score_kernel<<<nrows / 4, 256, 0, stream>>>(feat, W, bias, score, nrows);

  // K2': fused peaks+scan+gather. 8 batches x 32 slices = 256 blocks
  scan_gather_kernel<<<B_DIM * 32, 1024, 0, stream>>>(feat, score, out, hlens_f);
}